// Round 6
// baseline (125.388 us; speedup 1.0000x reference)
//
#include <hip/hip_runtime.h>

#define Bb 4
#define Cc 256
#define GC_ 64
#define Hh 128
#define Wd 128
#define HWn 16384
#define NPIX 65536
#define EPS 1e-5f

// workspace layout (float offsets). T region holds t (bf16) then xbf (bf16).
#define T_OFF   0
#define E_OFF   16777216
#define ST_OFF  (E_OFF + NPIX*4)
#define A_OFF   (ST_OFF + 16)
#define CV_OFF  (A_OFF + 16384)
#define FW_OFF  (CV_OFF + 256)
#define ALP_OFF (FW_OFF + 1024)
#define BET_OFF (ALP_OFF + 256)

typedef __attribute__((ext_vector_type(8))) short short8v;
typedef __attribute__((ext_vector_type(4))) float f32x4;
typedef unsigned short u16;

__device__ inline u16 f2bf(float f) {
    union { float f; unsigned u; } v; v.f = f;
    unsigned r = v.u + 0x7fff + ((v.u >> 16) & 1);   // RNE
    return (u16)(r >> 16);
}
__device__ inline float bf2f(u16 u) {
    union { unsigned u; float f; } v; v.u = ((unsigned)u) << 16;
    return v.f;
}

// K0: A_g = qw_g^T @ kw_g ; cvec_g = qw_g^T (sum_r rk_g) ; fwred[o][i] = sum_c fusion_w[o, i*64+c]
// block 4 also zeroes stats.
__global__ __launch_bounds__(256) void k0_precompute(
    const float* __restrict__ qw, const float* __restrict__ kw,
    const float* __restrict__ rk0, const float* __restrict__ rk1,
    const float* __restrict__ rk2, const float* __restrict__ rk3,
    const float* __restrict__ fusion_w,
    float* __restrict__ A, float* __restrict__ cvec, float* __restrict__ fwred,
    float* __restrict__ stats)
{
    const int tid = threadIdx.x;
    if (blockIdx.x == 4) {
        if (tid < 16) stats[tid] = 0.f;
        for (int i = 0; i < 4; ++i) {
            float s = 0.f;
            const float* fp = fusion_w + tid*256 + i*64;
            #pragma unroll 8
            for (int c = 0; c < 64; ++c) s += fp[c];
            fwred[tid*4 + i] = s;
        }
        return;
    }
    const int g = blockIdx.x;
    __shared__ float qwL[4096];
    __shared__ float kwL[4096];
    __shared__ float rks[64];
    for (int i = tid; i < 4096; i += 256) {
        qwL[i] = qw[g*4096 + i];
        kwL[i] = kw[g*4096 + i];
    }
    __syncthreads();
    if (tid < 64) {
        const float* rkp = (g==0)?rk0:(g==1)?rk1:(g==2)?rk2:rk3;
        const int R = 4*g + 9;               // 2L-1 for L={5,7,9,11}
        float s = 0.f;
        for (int r = 0; r < R; ++r) s += rkp[tid*R + r];
        rks[tid] = s;
    }
    __syncthreads();
    for (int idx = tid; idx < 4096; idx += 256) {
        const int c = idx >> 6, d = idx & 63;
        float s = 0.f;
        #pragma unroll
        for (int o = 0; o < 64; ++o) s += qwL[o*64 + c] * kwL[o*64 + d];
        A[g*4096 + idx] = s;
    }
    if (tid < 64) {
        float s = 0.f;
        #pragma unroll
        for (int o = 0; o < 64; ++o) s += qwL[o*64 + tid] * rks[o];
        cvec[g*64 + tid] = s;
    }
}

// K1 (MFMA, swapped operands) + coalesced bf16 cast of x.
// t[b, g*64+o, p] = sum_d A_g[o][d] * x[b, g*64+d, p]; also xbf = bf16(x) for k3/k5.
__global__ __launch_bounds__(256) void k1_mfma(
    const float* __restrict__ x, const float* __restrict__ A,
    u16* __restrict__ t, u16* __restrict__ xbf)
{
    const int tid = threadIdx.x;
    const int wv = tid >> 6, lane = tid & 63;
    const int chunk = blockIdx.x & 63;
    const int g = (blockIdx.x >> 6) & 3;
    const int b = blockIdx.x >> 8;
    const int l15 = lane & 15, lg = lane >> 4;

    const float* xg = x   + (size_t)(b*Cc + g*GC_)*HWn;
    u16* tg        = t    + (size_t)(b*Cc + g*GC_)*HWn;
    u16* xbg       = xbf  + (size_t)(b*Cc + g*GC_)*HWn;
    const int pxb = chunk*256;

    // coalesced bf16 cast of this block's x slab (64 ch x 256 px), L2-hot with frag loads
    for (int i = tid; i < 4096; i += 256) {     // 64 ch * 64 float4
        const int c = i >> 6, j = (i & 63) << 2;
        const float4 v = *(const float4*)(xg + (size_t)c*HWn + pxb + j);
        u16 o4[4] __attribute__((aligned(8))) = {f2bf(v.x), f2bf(v.y), f2bf(v.z), f2bf(v.w)};
        *(uint2*)(xbg + (size_t)c*HWn + pxb + j) = *(const uint2*)o4;
    }

    const float* Ag = A + g*4096;
    short8v afr[4][2];   // Ag[ct*16+l15][kh*32+lg*8+j]  (B-operand)
    #pragma unroll
    for (int ct = 0; ct < 4; ++ct)
      #pragma unroll
      for (int kh = 0; kh < 2; ++kh) {
        const float* ap = Ag + (ct*16 + l15)*64 + kh*32 + lg*8;
        #pragma unroll
        for (int j = 0; j < 8; ++j) afr[ct][kh][j] = (short)f2bf(ap[j]);
      }

    const int px0 = pxb + wv*64;
    #pragma unroll
    for (int nt = 0; nt < 4; ++nt) {
        const int pn = px0 + nt*16 + l15;
        short8v bfr[2];  // X[kh*32+lg*8+j][pn]  (A-operand)
        #pragma unroll
        for (int kh = 0; kh < 2; ++kh) {
            const float* xp = xg + (size_t)(kh*32 + lg*8)*HWn + pn;
            #pragma unroll
            for (int j = 0; j < 8; ++j) bfr[kh][j] = (short)f2bf(xp[j*HWn]);
        }
        #pragma unroll
        for (int ct = 0; ct < 4; ++ct) {
            f32x4 acc = {0.f, 0.f, 0.f, 0.f};
            acc = __builtin_amdgcn_mfma_f32_16x16x32_bf16(bfr[0], afr[ct][0], acc, 0, 0, 0);
            acc = __builtin_amdgcn_mfma_f32_16x16x32_bf16(bfr[1], afr[ct][1], acc, 0, 0, 0);
            u16 ov[4] __attribute__((aligned(8)));
            #pragma unroll
            for (int r = 0; r < 4; ++r) ov[r] = f2bf(acc[r]);
            *(uint2*)(tg + (size_t)(ct*16 + l15)*HWn + px0 + nt*16 + lg*4) = *(const uint2*)ov;
        }
    }
}

// K2: S = vbox_L(t) + hbox_L(t) - t via O(1) sliding windows. bf16 LDS (19.5KB -> 8 blocks/CU).
#define TROW 132
__global__ __launch_bounds__(256) void k2_cross(
    const u16* __restrict__ t, u16* __restrict__ S)
{
    __shared__ u16 timg[42*TROW];
    __shared__ u16 simg[32*TROW];
    const int tid = threadIdx.x;
    const int bid = blockIdx.x;
    const int wk = (bid & 7)*512 + (bid >> 3);    // 4096 = 8*512, bijective
    const int tile = wk & 3;
    const int bc = wk >> 2;
    const int g = (bc & 255) >> 6;
    const int p = g + 2;              // pad = {2,3,4,5}
    const int h0 = tile * 32;
    const int nrows = 32 + 2*p;
    const u16* tp = t + (size_t)bc*HWn;

    for (int idx = tid; idx < nrows*32; idx += 256) {
        const int r = idx >> 5, w4 = (idx & 31) << 2;
        const int hh = h0 - p + r;
        uint2 v = make_uint2(0u, 0u);
        if (hh >= 0 && hh < 128) v = *(const uint2*)(tp + (hh<<7) + w4);
        *(uint2*)(timg + r*TROW + w4) = v;
    }
    __syncthreads();

    {
        const int w = tid & 127;
        const int half = tid >> 7;
        const int rbase = half * 16;
        float run = 0.f;
        for (int j = 0; j <= 2*p; ++j) run += bf2f(timg[(rbase + j)*TROW + w]);
        #pragma unroll
        for (int i = 0; i < 16; ++i) {
            simg[(rbase + i)*TROW + w] = f2bf(run);
            if (i != 15)
                run += bf2f(timg[(rbase + i + 1 + 2*p)*TROW + w])
                     - bf2f(timg[(rbase + i)*TROW + w]);
        }
    }
    __syncthreads();

    {
        const int r8 = tid >> 3;
        const int seg = tid & 7;
        const int w0 = seg * 16;
        const u16* trow = timg + (r8 + p)*TROW;
        float run = 0.f;
        const int lo = max(w0 - p, 0), hi = min(w0 + p, 127);
        for (int ww = lo; ww <= hi; ++ww) run += bf2f(trow[ww]);
        u16 ov[16] __attribute__((aligned(16)));
        #pragma unroll
        for (int j = 0; j < 16; ++j) {
            const int w = w0 + j;
            const float sv = bf2f(simg[r8*TROW + w]);
            ov[j] = f2bf(run + sv - bf2f(trow[w]));
            run += (w + 1 + p < 128 ? bf2f(trow[w + 1 + p]) : 0.f)
                 - (w - p     >= 0  ? bf2f(trow[w - p])     : 0.f);
        }
        uint4* dst = (uint4*)(S + (size_t)bc*HWn + ((h0 + r8) << 7) + w0);
        dst[0] = ((const uint4*)ov)[0];
        dst[1] = ((const uint4*)ov)[1];
    }
}

// K3: e[b,g,p] = sum_c (x_c+rq_c)(S_c+cv_c), xbf/S bf16, planar f32 output
__global__ __launch_bounds__(256) void k3_e(
    const u16* __restrict__ xbf, const u16* __restrict__ S,
    const float* __restrict__ r_q, const float* __restrict__ cvec,
    float* __restrict__ ebuf)
{
    const int tid = threadIdx.x;
    const int chunk = blockIdx.x & 63;
    const int g = (blockIdx.x >> 6) & 3;
    const int b = blockIdx.x >> 8;
    __shared__ float rqL[64], cvL[64];
    if (tid < 64) { rqL[tid] = r_q[g*64 + tid]; cvL[tid] = cvec[g*64 + tid]; }
    __syncthreads();
    const int p = chunk*256 + tid;
    const u16* xp = xbf + (size_t)(b*Cc + g*GC_)*HWn + p;
    const u16* Sp = S   + (size_t)(b*Cc + g*GC_)*HWn + p;
    float acc = 0.f;
    #pragma unroll 16
    for (int c = 0; c < 64; ++c)
        acc += (bf2f(xp[c*HWn]) + rqL[c]) * (bf2f(Sp[c*HWn]) + cvL[c]);
    ebuf[(b*4 + g)*HWn + p] = acc;
}

// K3b: 4x4 moment matrix of e (14 scalars)
__global__ __launch_bounds__(256) void k3b_stats(
    const float* __restrict__ ebuf, float* __restrict__ stats)
{
    __shared__ float red[4*14];
    const int tid = threadIdx.x;
    const int q = blockIdx.x*256 + tid;
    const int b = q >> 14, p = q & (HWn - 1);
    const float* eb = ebuf + (size_t)b*4*HWn;
    const float e0 = eb[0*HWn + p], e1 = eb[1*HWn + p], e2 = eb[2*HWn + p], e3 = eb[3*HWn + p];
    float v[14];
    v[0]=e0; v[1]=e1; v[2]=e2; v[3]=e3;
    v[4]=e0*e0; v[5]=e0*e1; v[6]=e0*e2; v[7]=e0*e3;
    v[8]=e1*e1; v[9]=e1*e2; v[10]=e1*e3;
    v[11]=e2*e2; v[12]=e2*e3; v[13]=e3*e3;
    #pragma unroll
    for (int kk = 0; kk < 14; ++kk) {
        float s = v[kk];
        for (int off = 32; off > 0; off >>= 1) s += __shfl_down(s, off, 64);
        v[kk] = s;
    }
    const int lane = tid & 63, wv = tid >> 6;
    if (lane == 0) {
        #pragma unroll
        for (int kk = 0; kk < 14; ++kk) red[wv*14 + kk] = v[kk];
    }
    __syncthreads();
    if (tid < 14) atomicAdd(&stats[tid], red[tid] + red[14+tid] + red[28+tid] + red[42+tid]);
}

// K5: out = x * sigmoid(relu(alpha*(fwred·e)+beta2)); 8 channels/block (ebuf reuse x8),
// BN-fold (old k4) computed inline from the 14 stats.
__global__ __launch_bounds__(256) void k5_out(
    const u16* __restrict__ xbf, const float* __restrict__ ebuf,
    const float* __restrict__ fwred, const float* __restrict__ stats,
    const float* __restrict__ gamma, const float* __restrict__ beta,
    float* __restrict__ out)
{
    const int tid = threadIdx.x;
    const int chunk = blockIdx.x & 15;
    const int oct = (blockIdx.x >> 4) & 31;
    const int b = blockIdx.x >> 9;
    __shared__ float alL[8], beL[8];
    __shared__ float4 fwL[8];
    if (tid < 8) {
        const int o = oct*8 + tid;
        const float invN = 1.f / (float)NPIX;
        const float me0 = stats[0]*invN, me1 = stats[1]*invN, me2 = stats[2]*invN, me3 = stats[3]*invN;
        const float m00 = stats[4]*invN,  m01 = stats[5]*invN,  m02 = stats[6]*invN,  m03 = stats[7]*invN;
        const float m11 = stats[8]*invN,  m12 = stats[9]*invN,  m13 = stats[10]*invN;
        const float m22 = stats[11]*invN, m23 = stats[12]*invN, m33 = stats[13]*invN;
        const float4 fw = ((const float4*)fwred)[o];
        const float Ef = fw.x*me0 + fw.y*me1 + fw.z*me2 + fw.w*me3;
        const float E2 = fw.x*fw.x*m00 + fw.y*fw.y*m11 + fw.z*fw.z*m22 + fw.w*fw.w*m33
                       + 2.f*(fw.x*fw.y*m01 + fw.x*fw.z*m02 + fw.x*fw.w*m03
                            + fw.y*fw.z*m12 + fw.y*fw.w*m13 + fw.z*fw.w*m23);
        const float a = gamma[o] * rsqrtf(E2 - Ef*Ef + EPS);
        alL[tid] = a;
        beL[tid] = beta[o] - Ef*a;
        fwL[tid] = fw;
    }
    __syncthreads();

    const int p0 = chunk*1024 + tid*4;
    const float* eb = ebuf + (size_t)b*4*HWn;
    const float4 E0 = *(const float4*)(eb + 0*HWn + p0);
    const float4 E1 = *(const float4*)(eb + 1*HWn + p0);
    const float4 E2v = *(const float4*)(eb + 2*HWn + p0);
    const float4 E3 = *(const float4*)(eb + 3*HWn + p0);

    #pragma unroll
    for (int c = 0; c < 8; ++c) {
        const int o = oct*8 + c;
        const float4 fw = fwL[c];
        const float al = alL[c], be = beL[c];
        float f[4];
        f[0] = fw.x*E0.x + fw.y*E1.x + fw.z*E2v.x + fw.w*E3.x;
        f[1] = fw.x*E0.y + fw.y*E1.y + fw.z*E2v.y + fw.w*E3.y;
        f[2] = fw.x*E0.z + fw.y*E1.z + fw.z*E2v.z + fw.w*E3.z;
        f[3] = fw.x*E0.w + fw.y*E1.w + fw.z*E2v.w + fw.w*E3.w;
        const size_t base = (size_t)(b*Cc + o)*HWn + p0;
        const uint2 xu = *(const uint2*)(xbf + base);
        float xa[4];
        xa[0] = bf2f((u16)(xu.x & 0xffff)); xa[1] = bf2f((u16)(xu.x >> 16));
        xa[2] = bf2f((u16)(xu.y & 0xffff)); xa[3] = bf2f((u16)(xu.y >> 16));
        float4 r; float* rp = &r.x;
        #pragma unroll
        for (int j = 0; j < 4; ++j) {
            float z = al*f[j] + be;
            z = fmaxf(z, 0.f);
            rp[j] = xa[j] / (1.f + __expf(-z));
        }
        *(float4*)(out + base) = r;
    }
}

extern "C" void kernel_launch(void* const* d_in, const int* in_sizes, int n_in,
                              void* d_out, int out_size, void* d_ws, size_t ws_size,
                              hipStream_t stream)
{
    const float* x   = (const float*)d_in[0];
    const float* qw  = (const float*)d_in[1];
    const float* kw  = (const float*)d_in[2];
    const float* r_q = (const float*)d_in[3];
    const float* rk0 = (const float*)d_in[4];
    const float* rk1 = (const float*)d_in[5];
    const float* rk2 = (const float*)d_in[6];
    const float* rk3 = (const float*)d_in[7];
    const float* fw  = (const float*)d_in[8];
    const float* gm  = (const float*)d_in[9];
    const float* bt  = (const float*)d_in[10];
    float* out = (float*)d_out;
    float* ws  = (float*)d_ws;

    u16*   t     = (u16*)(ws + T_OFF);          // bf16 t, 33.5 MB
    u16*   xbf   = (u16*)ws + 16777216;         // bf16 x copy, second half of T region
    float* ebuf  = ws + E_OFF;
    float* stats = ws + ST_OFF;
    float* A     = ws + A_OFF;
    float* cvec  = ws + CV_OFF;
    float* fwr   = ws + FW_OFF;
    u16*   Sbuf  = (u16*)out;                   // S staged bf16 in d_out, overwritten by k5

    k0_precompute<<<5,    256, 0, stream>>>(qw, kw, rk0, rk1, rk2, rk3, fw, A, cvec, fwr, stats);
    k1_mfma      <<<1024, 256, 0, stream>>>(x, A, t, xbf);
    k2_cross     <<<4096, 256, 0, stream>>>(t, Sbuf);
    k3_e         <<<1024, 256, 0, stream>>>(xbf, Sbuf, r_q, cvec, ebuf);
    k3b_stats    <<<256,  256, 0, stream>>>(ebuf, stats);
    k5_out       <<<2048, 256, 0, stream>>>(xbf, ebuf, fwr, stats, gm, bt, out);
}

// Round 7
// 118.847 us; speedup vs baseline: 1.0550x; 1.0550x over previous
//
#include <hip/hip_runtime.h>

#define Bb 4
#define Cc 256
#define GC_ 64
#define Hh 128
#define Wd 128
#define HWn 16384
#define NPIX 65536
#define EPS 1e-5f

// workspace layout (float offsets). T region holds t (bf16) then xbf (bf16).
#define T_OFF   0
#define E_OFF   16777216
#define ST_OFF  (E_OFF + NPIX*4)
#define A_OFF   (ST_OFF + 16)
#define CV_OFF  (A_OFF + 16384)
#define FW_OFF  (CV_OFF + 256)

typedef __attribute__((ext_vector_type(8))) short short8v;
typedef __attribute__((ext_vector_type(4))) float f32x4;
typedef unsigned short u16;

__device__ inline u16 f2bf(float f) {
    union { float f; unsigned u; } v; v.f = f;
    unsigned r = v.u + 0x7fff + ((v.u >> 16) & 1);   // RNE
    return (u16)(r >> 16);
}
__device__ inline float bf2f(u16 u) {
    union { unsigned u; float f; } v; v.u = ((unsigned)u) << 16;
    return v.f;
}

// K0: A_g = qw_g^T @ kw_g ; cvec_g = qw_g^T (sum_r rk_g) ; fwred[o][i] = sum_c fusion_w[o, i*64+c]
// block 4 also zeroes stats.
__global__ __launch_bounds__(256) void k0_precompute(
    const float* __restrict__ qw, const float* __restrict__ kw,
    const float* __restrict__ rk0, const float* __restrict__ rk1,
    const float* __restrict__ rk2, const float* __restrict__ rk3,
    const float* __restrict__ fusion_w,
    float* __restrict__ A, float* __restrict__ cvec, float* __restrict__ fwred,
    float* __restrict__ stats)
{
    const int tid = threadIdx.x;
    if (blockIdx.x == 4) {
        if (tid < 16) stats[tid] = 0.f;
        for (int i = 0; i < 4; ++i) {
            float s = 0.f;
            const float* fp = fusion_w + tid*256 + i*64;
            #pragma unroll 8
            for (int c = 0; c < 64; ++c) s += fp[c];
            fwred[tid*4 + i] = s;
        }
        return;
    }
    const int g = blockIdx.x;
    __shared__ float qwL[4096];
    __shared__ float kwL[4096];
    __shared__ float rks[64];
    for (int i = tid; i < 4096; i += 256) {
        qwL[i] = qw[g*4096 + i];
        kwL[i] = kw[g*4096 + i];
    }
    __syncthreads();
    if (tid < 64) {
        const float* rkp = (g==0)?rk0:(g==1)?rk1:(g==2)?rk2:rk3;
        const int R = 4*g + 9;               // 2L-1 for L={5,7,9,11}
        float s = 0.f;
        for (int r = 0; r < R; ++r) s += rkp[tid*R + r];
        rks[tid] = s;
    }
    __syncthreads();
    for (int idx = tid; idx < 4096; idx += 256) {
        const int c = idx >> 6, d = idx & 63;
        float s = 0.f;
        #pragma unroll
        for (int o = 0; o < 64; ++o) s += qwL[o*64 + c] * kwL[o*64 + d];
        A[g*4096 + idx] = s;
    }
    if (tid < 64) {
        float s = 0.f;
        #pragma unroll
        for (int o = 0; o < 64; ++o) s += qwL[o*64 + tid] * rks[o];
        cvec[g*64 + tid] = s;
    }
}

// K1 (MFMA): t[b, g*64+o, p] = sum_d A_g[o][d] * x[b, g*64+d, p]; xbf = bf16(x).
// x is read ONCE (coalesced float4), cast bf16, written to LDS tile [64ch][pitch132]
// + xbf. MFMA B-frags (X as A-operand) come from LDS (2-way bank alias = free).
// 128 px per block -> grid 2048, LDS 16.9KB -> 8 blocks/CU.
__global__ __launch_bounds__(256) void k1_mfma(
    const float* __restrict__ x, const float* __restrict__ A,
    u16* __restrict__ t, u16* __restrict__ xbf)
{
    __shared__ u16 xt[64*132];
    const int tid = threadIdx.x;
    const int wv = tid >> 6, lane = tid & 63;
    const int chunk = blockIdx.x & 127;
    const int g = (blockIdx.x >> 7) & 3;
    const int b = blockIdx.x >> 9;
    const int l15 = lane & 15, lg = lane >> 4;
    const int px0 = chunk*128;

    const float* xg = x   + (size_t)(b*Cc + g*GC_)*HWn;
    u16* tg        = t    + (size_t)(b*Cc + g*GC_)*HWn;
    u16* xbg       = xbf  + (size_t)(b*Cc + g*GC_)*HWn;

    // stage: 64ch x 128px, one pass
    #pragma unroll
    for (int i = 0; i < 8; ++i) {
        const int idx = tid + i*256;
        const int ch = idx >> 5, q = (idx & 31) << 2;
        const float4 v = *(const float4*)(xg + (size_t)ch*HWn + px0 + q);
        u16 o4[4] __attribute__((aligned(8))) = {f2bf(v.x), f2bf(v.y), f2bf(v.z), f2bf(v.w)};
        *(uint2*)(xt + ch*132 + q) = *(const uint2*)o4;
        *(uint2*)(xbg + (size_t)ch*HWn + px0 + q) = *(const uint2*)o4;
    }

    // A-matrix frags (B-operand), L2-hot scalar loads
    const float* Ag = A + g*4096;
    short8v afr[4][2];   // Ag[ct*16+l15][kh*32+lg*8+j]
    #pragma unroll
    for (int ct = 0; ct < 4; ++ct)
      #pragma unroll
      for (int kh = 0; kh < 2; ++kh) {
        const float* ap = Ag + (ct*16 + l15)*64 + kh*32 + lg*8;
        #pragma unroll
        for (int j = 0; j < 8; ++j) afr[ct][kh][j] = (short)f2bf(ap[j]);
      }

    __syncthreads();

    const int pw = wv*32;           // wave's 32-px window in the tile
    #pragma unroll
    for (int nt = 0; nt < 2; ++nt) {
        const int pt = pw + nt*16 + l15;
        short8v bfr[2];             // X[kh*32+lg*8+j][pt] from LDS
        #pragma unroll
        for (int kh = 0; kh < 2; ++kh)
          #pragma unroll
          for (int j = 0; j < 8; ++j)
            bfr[kh][j] = (short)xt[(kh*32 + lg*8 + j)*132 + pt];
        #pragma unroll
        for (int ct = 0; ct < 4; ++ct) {
            f32x4 acc = {0.f, 0.f, 0.f, 0.f};
            acc = __builtin_amdgcn_mfma_f32_16x16x32_bf16(bfr[0], afr[ct][0], acc, 0, 0, 0);
            acc = __builtin_amdgcn_mfma_f32_16x16x32_bf16(bfr[1], afr[ct][1], acc, 0, 0, 0);
            u16 ov[4] __attribute__((aligned(8)));
            #pragma unroll
            for (int r = 0; r < 4; ++r) ov[r] = f2bf(acc[r]);
            *(uint2*)(tg + (size_t)(ct*16 + l15)*HWn + px0 + pw + nt*16 + lg*4) = *(const uint2*)ov;
        }
    }
}

// K2: S = vbox_L(t) + hbox_L(t) - t via O(1) sliding windows. bf16 LDS (19.5KB -> 8 blocks/CU).
#define TROW 132
__global__ __launch_bounds__(256) void k2_cross(
    const u16* __restrict__ t, u16* __restrict__ S)
{
    __shared__ u16 timg[42*TROW];
    __shared__ u16 simg[32*TROW];
    const int tid = threadIdx.x;
    const int bid = blockIdx.x;
    const int wk = (bid & 7)*512 + (bid >> 3);    // 4096 = 8*512, bijective
    const int tile = wk & 3;
    const int bc = wk >> 2;
    const int g = (bc & 255) >> 6;
    const int p = g + 2;              // pad = {2,3,4,5}
    const int h0 = tile * 32;
    const int nrows = 32 + 2*p;
    const u16* tp = t + (size_t)bc*HWn;

    for (int idx = tid; idx < nrows*32; idx += 256) {
        const int r = idx >> 5, w4 = (idx & 31) << 2;
        const int hh = h0 - p + r;
        uint2 v = make_uint2(0u, 0u);
        if (hh >= 0 && hh < 128) v = *(const uint2*)(tp + (hh<<7) + w4);
        *(uint2*)(timg + r*TROW + w4) = v;
    }
    __syncthreads();

    {
        const int w = tid & 127;
        const int half = tid >> 7;
        const int rbase = half * 16;
        float run = 0.f;
        for (int j = 0; j <= 2*p; ++j) run += bf2f(timg[(rbase + j)*TROW + w]);
        #pragma unroll
        for (int i = 0; i < 16; ++i) {
            simg[(rbase + i)*TROW + w] = f2bf(run);
            if (i != 15)
                run += bf2f(timg[(rbase + i + 1 + 2*p)*TROW + w])
                     - bf2f(timg[(rbase + i)*TROW + w]);
        }
    }
    __syncthreads();

    {
        const int r8 = tid >> 3;
        const int seg = tid & 7;
        const int w0 = seg * 16;
        const u16* trow = timg + (r8 + p)*TROW;
        float run = 0.f;
        const int lo = max(w0 - p, 0), hi = min(w0 + p, 127);
        for (int ww = lo; ww <= hi; ++ww) run += bf2f(trow[ww]);
        u16 ov[16] __attribute__((aligned(16)));
        #pragma unroll
        for (int j = 0; j < 16; ++j) {
            const int w = w0 + j;
            const float sv = bf2f(simg[r8*TROW + w]);
            ov[j] = f2bf(run + sv - bf2f(trow[w]));
            run += (w + 1 + p < 128 ? bf2f(trow[w + 1 + p]) : 0.f)
                 - (w - p     >= 0  ? bf2f(trow[w - p])     : 0.f);
        }
        uint4* dst = (uint4*)(S + (size_t)bc*HWn + ((h0 + r8) << 7) + w0);
        dst[0] = ((const uint4*)ov)[0];
        dst[1] = ((const uint4*)ov)[1];
    }
}

// K3: e[b,g,p] = sum_c (x_c+rq_c)(S_c+cv_c), xbf/S bf16, planar f32 output
__global__ __launch_bounds__(256) void k3_e(
    const u16* __restrict__ xbf, const u16* __restrict__ S,
    const float* __restrict__ r_q, const float* __restrict__ cvec,
    float* __restrict__ ebuf)
{
    const int tid = threadIdx.x;
    const int chunk = blockIdx.x & 63;
    const int g = (blockIdx.x >> 6) & 3;
    const int b = blockIdx.x >> 8;
    __shared__ float rqL[64], cvL[64];
    if (tid < 64) { rqL[tid] = r_q[g*64 + tid]; cvL[tid] = cvec[g*64 + tid]; }
    __syncthreads();
    const int p = chunk*256 + tid;
    const u16* xp = xbf + (size_t)(b*Cc + g*GC_)*HWn + p;
    const u16* Sp = S   + (size_t)(b*Cc + g*GC_)*HWn + p;
    float acc = 0.f;
    #pragma unroll 16
    for (int c = 0; c < 64; ++c)
        acc += (bf2f(xp[c*HWn]) + rqL[c]) * (bf2f(Sp[c*HWn]) + cvL[c]);
    ebuf[(b*4 + g)*HWn + p] = acc;
}

// K3b: 4x4 moment matrix of e (14 scalars)
__global__ __launch_bounds__(256) void k3b_stats(
    const float* __restrict__ ebuf, float* __restrict__ stats)
{
    __shared__ float red[4*14];
    const int tid = threadIdx.x;
    const int q = blockIdx.x*256 + tid;
    const int b = q >> 14, p = q & (HWn - 1);
    const float* eb = ebuf + (size_t)b*4*HWn;
    const float e0 = eb[0*HWn + p], e1 = eb[1*HWn + p], e2 = eb[2*HWn + p], e3 = eb[3*HWn + p];
    float v[14];
    v[0]=e0; v[1]=e1; v[2]=e2; v[3]=e3;
    v[4]=e0*e0; v[5]=e0*e1; v[6]=e0*e2; v[7]=e0*e3;
    v[8]=e1*e1; v[9]=e1*e2; v[10]=e1*e3;
    v[11]=e2*e2; v[12]=e2*e3; v[13]=e3*e3;
    #pragma unroll
    for (int kk = 0; kk < 14; ++kk) {
        float s = v[kk];
        for (int off = 32; off > 0; off >>= 1) s += __shfl_down(s, off, 64);
        v[kk] = s;
    }
    const int lane = tid & 63, wv = tid >> 6;
    if (lane == 0) {
        #pragma unroll
        for (int kk = 0; kk < 14; ++kk) red[wv*14 + kk] = v[kk];
    }
    __syncthreads();
    if (tid < 14) atomicAdd(&stats[tid], red[tid] + red[14+tid] + red[28+tid] + red[42+tid]);
}

// K5: out = x * sigmoid(relu(alpha*(fwred·e)+beta2)); 8 channels/block (ebuf reuse x8),
// BN-fold computed inline from the 14 stats.
__global__ __launch_bounds__(256) void k5_out(
    const u16* __restrict__ xbf, const float* __restrict__ ebuf,
    const float* __restrict__ fwred, const float* __restrict__ stats,
    const float* __restrict__ gamma, const float* __restrict__ beta,
    float* __restrict__ out)
{
    const int tid = threadIdx.x;
    const int chunk = blockIdx.x & 15;
    const int oct = (blockIdx.x >> 4) & 31;
    const int b = blockIdx.x >> 9;
    __shared__ float alL[8], beL[8];
    __shared__ float4 fwL[8];
    if (tid < 8) {
        const int o = oct*8 + tid;
        const float invN = 1.f / (float)NPIX;
        const float me0 = stats[0]*invN, me1 = stats[1]*invN, me2 = stats[2]*invN, me3 = stats[3]*invN;
        const float m00 = stats[4]*invN,  m01 = stats[5]*invN,  m02 = stats[6]*invN,  m03 = stats[7]*invN;
        const float m11 = stats[8]*invN,  m12 = stats[9]*invN,  m13 = stats[10]*invN;
        const float m22 = stats[11]*invN, m23 = stats[12]*invN, m33 = stats[13]*invN;
        const float4 fw = ((const float4*)fwred)[o];
        const float Ef = fw.x*me0 + fw.y*me1 + fw.z*me2 + fw.w*me3;
        const float E2 = fw.x*fw.x*m00 + fw.y*fw.y*m11 + fw.z*fw.z*m22 + fw.w*fw.w*m33
                       + 2.f*(fw.x*fw.y*m01 + fw.x*fw.z*m02 + fw.x*fw.w*m03
                            + fw.y*fw.z*m12 + fw.y*fw.w*m13 + fw.z*fw.w*m23);
        const float a = gamma[o] * rsqrtf(E2 - Ef*Ef + EPS);
        alL[tid] = a;
        beL[tid] = beta[o] - Ef*a;
        fwL[tid] = fw;
    }
    __syncthreads();

    const int p0 = chunk*1024 + tid*4;
    const float* eb = ebuf + (size_t)b*4*HWn;
    const float4 E0 = *(const float4*)(eb + 0*HWn + p0);
    const float4 E1 = *(const float4*)(eb + 1*HWn + p0);
    const float4 E2v = *(const float4*)(eb + 2*HWn + p0);
    const float4 E3 = *(const float4*)(eb + 3*HWn + p0);

    #pragma unroll
    for (int c = 0; c < 8; ++c) {
        const int o = oct*8 + c;
        const float4 fw = fwL[c];
        const float al = alL[c], be = beL[c];
        float f[4];
        f[0] = fw.x*E0.x + fw.y*E1.x + fw.z*E2v.x + fw.w*E3.x;
        f[1] = fw.x*E0.y + fw.y*E1.y + fw.z*E2v.y + fw.w*E3.y;
        f[2] = fw.x*E0.z + fw.y*E1.z + fw.z*E2v.z + fw.w*E3.z;
        f[3] = fw.x*E0.w + fw.y*E1.w + fw.z*E2v.w + fw.w*E3.w;
        const size_t base = (size_t)(b*Cc + o)*HWn + p0;
        const uint2 xu = *(const uint2*)(xbf + base);
        float xa[4];
        xa[0] = bf2f((u16)(xu.x & 0xffff)); xa[1] = bf2f((u16)(xu.x >> 16));
        xa[2] = bf2f((u16)(xu.y & 0xffff)); xa[3] = bf2f((u16)(xu.y >> 16));
        float4 r; float* rp = &r.x;
        #pragma unroll
        for (int j = 0; j < 4; ++j) {
            float z = al*f[j] + be;
            z = fmaxf(z, 0.f);
            rp[j] = xa[j] / (1.f + __expf(-z));
        }
        *(float4*)(out + base) = r;
    }
}

extern "C" void kernel_launch(void* const* d_in, const int* in_sizes, int n_in,
                              void* d_out, int out_size, void* d_ws, size_t ws_size,
                              hipStream_t stream)
{
    const float* x   = (const float*)d_in[0];
    const float* qw  = (const float*)d_in[1];
    const float* kw  = (const float*)d_in[2];
    const float* r_q = (const float*)d_in[3];
    const float* rk0 = (const float*)d_in[4];
    const float* rk1 = (const float*)d_in[5];
    const float* rk2 = (const float*)d_in[6];
    const float* rk3 = (const float*)d_in[7];
    const float* fw  = (const float*)d_in[8];
    const float* gm  = (const float*)d_in[9];
    const float* bt  = (const float*)d_in[10];
    float* out = (float*)d_out;
    float* ws  = (float*)d_ws;

    u16*   t     = (u16*)(ws + T_OFF);          // bf16 t, 33.5 MB
    u16*   xbf   = (u16*)ws + 16777216;         // bf16 x copy, second half of T region
    float* ebuf  = ws + E_OFF;
    float* stats = ws + ST_OFF;
    float* A     = ws + A_OFF;
    float* cvec  = ws + CV_OFF;
    float* fwr   = ws + FW_OFF;
    u16*   Sbuf  = (u16*)out;                   // S staged bf16 in d_out, overwritten by k5

    k0_precompute<<<5,    256, 0, stream>>>(qw, kw, rk0, rk1, rk2, rk3, fw, A, cvec, fwr, stats);
    k1_mfma      <<<2048, 256, 0, stream>>>(x, A, t, xbf);
    k2_cross     <<<4096, 256, 0, stream>>>(t, Sbuf);
    k3_e         <<<1024, 256, 0, stream>>>(xbf, Sbuf, r_q, cvec, ebuf);
    k3b_stats    <<<256,  256, 0, stream>>>(ebuf, stats);
    k5_out       <<<2048, 256, 0, stream>>>(xbf, ebuf, fwr, stats, gm, bt, out);
}

// Round 8
// 109.939 us; speedup vs baseline: 1.1405x; 1.0810x over previous
//
#include <hip/hip_runtime.h>

#define Bb 4
#define Cc 256
#define GC_ 64
#define Hh 128
#define Wd 128
#define HWn 16384
#define NPIX 65536
#define EPS 1e-5f

// workspace layout (float offsets). T region holds t (bf16) then xbf (bf16).
#define T_OFF   0
#define E_OFF   16777216
#define ST_OFF  (E_OFF + NPIX*4)
#define A_OFF   (ST_OFF + 16)      // Abf: 16384 u16 = 32KB, fragment-packed
#define CV_OFF  (A_OFF + 16384)
#define FW_OFF  (CV_OFF + 256)

typedef __attribute__((ext_vector_type(8))) short short8v;
typedef __attribute__((ext_vector_type(4))) float f32x4;
typedef unsigned short u16;

__device__ inline u16 f2bf(float f) {
    union { float f; unsigned u; } v; v.f = f;
    unsigned r = v.u + 0x7fff + ((v.u >> 16) & 1);   // RNE
    return (u16)(r >> 16);
}
__device__ inline float bf2f(u16 u) {
    union { unsigned u; float f; } v; v.u = ((unsigned)u) << 16;
    return v.f;
}

// K0: Abf_g = bf16(qw_g^T @ kw_g) packed in MFMA-fragment order;
// cvec_g = qw_g^T (sum_r rk_g) ; fwred[o][i] = sum_c fusion_w[o, i*64+c].
// Abf element (ct,kh,lane,j): row c = ct*16+(lane&15), col d = kh*32+(lane>>4)*8+j
// -> k1 thread `lane` loads afr[ct][kh] as ONE 16B load.
__global__ __launch_bounds__(256) void k0_precompute(
    const float* __restrict__ qw, const float* __restrict__ kw,
    const float* __restrict__ rk0, const float* __restrict__ rk1,
    const float* __restrict__ rk2, const float* __restrict__ rk3,
    const float* __restrict__ fusion_w,
    u16* __restrict__ Abf, float* __restrict__ cvec, float* __restrict__ fwred,
    float* __restrict__ stats)
{
    const int tid = threadIdx.x;
    if (blockIdx.x == 4) {
        if (tid < 16) stats[tid] = 0.f;
        for (int i = 0; i < 4; ++i) {
            float s = 0.f;
            const float* fp = fusion_w + tid*256 + i*64;
            #pragma unroll 8
            for (int c = 0; c < 64; ++c) s += fp[c];
            fwred[tid*4 + i] = s;
        }
        return;
    }
    const int g = blockIdx.x;
    __shared__ float qwL[4096];
    __shared__ float kwL[4096];
    __shared__ float rks[64];
    for (int i = tid; i < 4096; i += 256) {
        qwL[i] = qw[g*4096 + i];
        kwL[i] = kw[g*4096 + i];
    }
    __syncthreads();
    if (tid < 64) {
        const float* rkp = (g==0)?rk0:(g==1)?rk1:(g==2)?rk2:rk3;
        const int R = 4*g + 9;               // 2L-1 for L={5,7,9,11}
        float s = 0.f;
        for (int r = 0; r < R; ++r) s += rkp[tid*R + r];
        rks[tid] = s;
    }
    __syncthreads();
    for (int idx = tid; idx < 4096; idx += 256) {
        const int ct = idx >> 10, kh = (idx >> 9) & 1;
        const int lane = (idx >> 3) & 63, j = idx & 7;
        const int c = ct*16 + (lane & 15);
        const int d = kh*32 + (lane >> 4)*8 + j;
        float s = 0.f;
        #pragma unroll
        for (int o = 0; o < 64; ++o) s += qwL[o*64 + c] * kwL[o*64 + d];
        Abf[g*4096 + idx] = f2bf(s);
    }
    if (tid < 64) {
        float s = 0.f;
        #pragma unroll
        for (int o = 0; o < 64; ++o) s += qwL[o*64 + tid] * rks[o];
        cvec[g*64 + tid] = s;
    }
}

// K1 (MFMA): t[b, g*64+o, p] = sum_d A_g[o][d] * x[b, g*64+d, p]; xbf = bf16(x).
// x read once (coalesced float4) -> LDS [64ch][132] + xbf. A-frags: 8 coalesced
// 16B loads from the prepacked Abf (no per-thread gather, no cvt).
__global__ __launch_bounds__(256) void k1_mfma(
    const float* __restrict__ x, const u16* __restrict__ Abf,
    u16* __restrict__ t, u16* __restrict__ xbf)
{
    __shared__ u16 xt[64*132];
    const int tid = threadIdx.x;
    const int wv = tid >> 6, lane = tid & 63;
    const int chunk = blockIdx.x & 127;
    const int g = (blockIdx.x >> 7) & 3;
    const int b = blockIdx.x >> 9;
    const int l15 = lane & 15, lg = lane >> 4;
    const int px0 = chunk*128;

    // A-fragments: one 16B load each, issued first to overlap the x staging
    const u16* Ab = Abf + g*4096;
    short8v afr[4][2];
    #pragma unroll
    for (int ct = 0; ct < 4; ++ct)
      #pragma unroll
      for (int kh = 0; kh < 2; ++kh)
        afr[ct][kh] = *(const short8v*)(Ab + ((ct*2 + kh)*64 + lane)*8);

    const float* xg = x   + (size_t)(b*Cc + g*GC_)*HWn;
    u16* tg        = t    + (size_t)(b*Cc + g*GC_)*HWn;
    u16* xbg       = xbf  + (size_t)(b*Cc + g*GC_)*HWn;

    // stage: 64ch x 128px, one pass
    #pragma unroll
    for (int i = 0; i < 8; ++i) {
        const int idx = tid + i*256;
        const int ch = idx >> 5, q = (idx & 31) << 2;
        const float4 v = *(const float4*)(xg + (size_t)ch*HWn + px0 + q);
        u16 o4[4] __attribute__((aligned(8))) = {f2bf(v.x), f2bf(v.y), f2bf(v.z), f2bf(v.w)};
        *(uint2*)(xt + ch*132 + q) = *(const uint2*)o4;
        *(uint2*)(xbg + (size_t)ch*HWn + px0 + q) = *(const uint2*)o4;
    }
    __syncthreads();

    const int pw = wv*32;           // wave's 32-px window in the tile
    #pragma unroll
    for (int nt = 0; nt < 2; ++nt) {
        const int pt = pw + nt*16 + l15;
        short8v bfr[2];             // X[kh*32+lg*8+j][pt] from LDS
        #pragma unroll
        for (int kh = 0; kh < 2; ++kh)
          #pragma unroll
          for (int j = 0; j < 8; ++j)
            bfr[kh][j] = (short)xt[(kh*32 + lg*8 + j)*132 + pt];
        #pragma unroll
        for (int ct = 0; ct < 4; ++ct) {
            f32x4 acc = {0.f, 0.f, 0.f, 0.f};
            acc = __builtin_amdgcn_mfma_f32_16x16x32_bf16(bfr[0], afr[ct][0], acc, 0, 0, 0);
            acc = __builtin_amdgcn_mfma_f32_16x16x32_bf16(bfr[1], afr[ct][1], acc, 0, 0, 0);
            u16 ov[4] __attribute__((aligned(8)));
            #pragma unroll
            for (int r = 0; r < 4; ++r) ov[r] = f2bf(acc[r]);
            *(uint2*)(tg + (size_t)(ct*16 + l15)*HWn + px0 + pw + nt*16 + lg*4) = *(const uint2*)ov;
        }
    }
}

// K2: S = vbox_L(t) + hbox_L(t) - t via O(1) sliding windows. bf16 LDS (19.5KB -> 8 blocks/CU).
#define TROW 132
__global__ __launch_bounds__(256) void k2_cross(
    const u16* __restrict__ t, u16* __restrict__ S)
{
    __shared__ u16 timg[42*TROW];
    __shared__ u16 simg[32*TROW];
    const int tid = threadIdx.x;
    const int bid = blockIdx.x;
    const int wk = (bid & 7)*512 + (bid >> 3);    // 4096 = 8*512, bijective
    const int tile = wk & 3;
    const int bc = wk >> 2;
    const int g = (bc & 255) >> 6;
    const int p = g + 2;              // pad = {2,3,4,5}
    const int h0 = tile * 32;
    const int nrows = 32 + 2*p;
    const u16* tp = t + (size_t)bc*HWn;

    for (int idx = tid; idx < nrows*32; idx += 256) {
        const int r = idx >> 5, w4 = (idx & 31) << 2;
        const int hh = h0 - p + r;
        uint2 v = make_uint2(0u, 0u);
        if (hh >= 0 && hh < 128) v = *(const uint2*)(tp + (hh<<7) + w4);
        *(uint2*)(timg + r*TROW + w4) = v;
    }
    __syncthreads();

    {
        const int w = tid & 127;
        const int half = tid >> 7;
        const int rbase = half * 16;
        float run = 0.f;
        for (int j = 0; j <= 2*p; ++j) run += bf2f(timg[(rbase + j)*TROW + w]);
        #pragma unroll
        for (int i = 0; i < 16; ++i) {
            simg[(rbase + i)*TROW + w] = f2bf(run);
            if (i != 15)
                run += bf2f(timg[(rbase + i + 1 + 2*p)*TROW + w])
                     - bf2f(timg[(rbase + i)*TROW + w]);
        }
    }
    __syncthreads();

    {
        const int r8 = tid >> 3;
        const int seg = tid & 7;
        const int w0 = seg * 16;
        const u16* trow = timg + (r8 + p)*TROW;
        float run = 0.f;
        const int lo = max(w0 - p, 0), hi = min(w0 + p, 127);
        for (int ww = lo; ww <= hi; ++ww) run += bf2f(trow[ww]);
        u16 ov[16] __attribute__((aligned(16)));
        #pragma unroll
        for (int j = 0; j < 16; ++j) {
            const int w = w0 + j;
            const float sv = bf2f(simg[r8*TROW + w]);
            ov[j] = f2bf(run + sv - bf2f(trow[w]));
            run += (w + 1 + p < 128 ? bf2f(trow[w + 1 + p]) : 0.f)
                 - (w - p     >= 0  ? bf2f(trow[w - p])     : 0.f);
        }
        uint4* dst = (uint4*)(S + (size_t)bc*HWn + ((h0 + r8) << 7) + w0);
        dst[0] = ((const uint4*)ov)[0];
        dst[1] = ((const uint4*)ov)[1];
    }
}

// K3: e[b,g,p] = sum_c (x_c+rq_c)(S_c+cv_c), xbf/S bf16, planar f32 output
__global__ __launch_bounds__(256) void k3_e(
    const u16* __restrict__ xbf, const u16* __restrict__ S,
    const float* __restrict__ r_q, const float* __restrict__ cvec,
    float* __restrict__ ebuf)
{
    const int tid = threadIdx.x;
    const int chunk = blockIdx.x & 63;
    const int g = (blockIdx.x >> 6) & 3;
    const int b = blockIdx.x >> 8;
    __shared__ float rqL[64], cvL[64];
    if (tid < 64) { rqL[tid] = r_q[g*64 + tid]; cvL[tid] = cvec[g*64 + tid]; }
    __syncthreads();
    const int p = chunk*256 + tid;
    const u16* xp = xbf + (size_t)(b*Cc + g*GC_)*HWn + p;
    const u16* Sp = S   + (size_t)(b*Cc + g*GC_)*HWn + p;
    float acc = 0.f;
    #pragma unroll 16
    for (int c = 0; c < 64; ++c)
        acc += (bf2f(xp[c*HWn]) + rqL[c]) * (bf2f(Sp[c*HWn]) + cvL[c]);
    ebuf[(b*4 + g)*HWn + p] = acc;
}

// K3b: 4x4 moment matrix of e (14 scalars)
__global__ __launch_bounds__(256) void k3b_stats(
    const float* __restrict__ ebuf, float* __restrict__ stats)
{
    __shared__ float red[4*14];
    const int tid = threadIdx.x;
    const int q = blockIdx.x*256 + tid;
    const int b = q >> 14, p = q & (HWn - 1);
    const float* eb = ebuf + (size_t)b*4*HWn;
    const float e0 = eb[0*HWn + p], e1 = eb[1*HWn + p], e2 = eb[2*HWn + p], e3 = eb[3*HWn + p];
    float v[14];
    v[0]=e0; v[1]=e1; v[2]=e2; v[3]=e3;
    v[4]=e0*e0; v[5]=e0*e1; v[6]=e0*e2; v[7]=e0*e3;
    v[8]=e1*e1; v[9]=e1*e2; v[10]=e1*e3;
    v[11]=e2*e2; v[12]=e2*e3; v[13]=e3*e3;
    #pragma unroll
    for (int kk = 0; kk < 14; ++kk) {
        float s = v[kk];
        for (int off = 32; off > 0; off >>= 1) s += __shfl_down(s, off, 64);
        v[kk] = s;
    }
    const int lane = tid & 63, wv = tid >> 6;
    if (lane == 0) {
        #pragma unroll
        for (int kk = 0; kk < 14; ++kk) red[wv*14 + kk] = v[kk];
    }
    __syncthreads();
    if (tid < 14) atomicAdd(&stats[tid], red[tid] + red[14+tid] + red[28+tid] + red[42+tid]);
}

// K5: out = x * sigmoid(relu(alpha*(fwred·e)+beta2)); 8 channels/block (ebuf reuse x8),
// BN-fold computed inline from the 14 stats.
__global__ __launch_bounds__(256) void k5_out(
    const u16* __restrict__ xbf, const float* __restrict__ ebuf,
    const float* __restrict__ fwred, const float* __restrict__ stats,
    const float* __restrict__ gamma, const float* __restrict__ beta,
    float* __restrict__ out)
{
    const int tid = threadIdx.x;
    const int chunk = blockIdx.x & 15;
    const int oct = (blockIdx.x >> 4) & 31;
    const int b = blockIdx.x >> 9;
    __shared__ float alL[8], beL[8];
    __shared__ float4 fwL[8];
    if (tid < 8) {
        const int o = oct*8 + tid;
        const float invN = 1.f / (float)NPIX;
        const float me0 = stats[0]*invN, me1 = stats[1]*invN, me2 = stats[2]*invN, me3 = stats[3]*invN;
        const float m00 = stats[4]*invN,  m01 = stats[5]*invN,  m02 = stats[6]*invN,  m03 = stats[7]*invN;
        const float m11 = stats[8]*invN,  m12 = stats[9]*invN,  m13 = stats[10]*invN;
        const float m22 = stats[11]*invN, m23 = stats[12]*invN, m33 = stats[13]*invN;
        const float4 fw = ((const float4*)fwred)[o];
        const float Ef = fw.x*me0 + fw.y*me1 + fw.z*me2 + fw.w*me3;
        const float E2 = fw.x*fw.x*m00 + fw.y*fw.y*m11 + fw.z*fw.z*m22 + fw.w*fw.w*m33
                       + 2.f*(fw.x*fw.y*m01 + fw.x*fw.z*m02 + fw.x*fw.w*m03
                            + fw.y*fw.z*m12 + fw.y*fw.w*m13 + fw.z*fw.w*m23);
        const float a = gamma[o] * rsqrtf(E2 - Ef*Ef + EPS);
        alL[tid] = a;
        beL[tid] = beta[o] - Ef*a;
        fwL[tid] = fw;
    }
    __syncthreads();

    const int p0 = chunk*1024 + tid*4;
    const float* eb = ebuf + (size_t)b*4*HWn;
    const float4 E0 = *(const float4*)(eb + 0*HWn + p0);
    const float4 E1 = *(const float4*)(eb + 1*HWn + p0);
    const float4 E2v = *(const float4*)(eb + 2*HWn + p0);
    const float4 E3 = *(const float4*)(eb + 3*HWn + p0);

    #pragma unroll
    for (int c = 0; c < 8; ++c) {
        const int o = oct*8 + c;
        const float4 fw = fwL[c];
        const float al = alL[c], be = beL[c];
        float f[4];
        f[0] = fw.x*E0.x + fw.y*E1.x + fw.z*E2v.x + fw.w*E3.x;
        f[1] = fw.x*E0.y + fw.y*E1.y + fw.z*E2v.y + fw.w*E3.y;
        f[2] = fw.x*E0.z + fw.y*E1.z + fw.z*E2v.z + fw.w*E3.z;
        f[3] = fw.x*E0.w + fw.y*E1.w + fw.z*E2v.w + fw.w*E3.w;
        const size_t base = (size_t)(b*Cc + o)*HWn + p0;
        const uint2 xu = *(const uint2*)(xbf + base);
        float xa[4];
        xa[0] = bf2f((u16)(xu.x & 0xffff)); xa[1] = bf2f((u16)(xu.x >> 16));
        xa[2] = bf2f((u16)(xu.y & 0xffff)); xa[3] = bf2f((u16)(xu.y >> 16));
        float4 r; float* rp = &r.x;
        #pragma unroll
        for (int j = 0; j < 4; ++j) {
            float z = al*f[j] + be;
            z = fmaxf(z, 0.f);
            rp[j] = xa[j] / (1.f + __expf(-z));
        }
        *(float4*)(out + base) = r;
    }
}

extern "C" void kernel_launch(void* const* d_in, const int* in_sizes, int n_in,
                              void* d_out, int out_size, void* d_ws, size_t ws_size,
                              hipStream_t stream)
{
    const float* x   = (const float*)d_in[0];
    const float* qw  = (const float*)d_in[1];
    const float* kw  = (const float*)d_in[2];
    const float* r_q = (const float*)d_in[3];
    const float* rk0 = (const float*)d_in[4];
    const float* rk1 = (const float*)d_in[5];
    const float* rk2 = (const float*)d_in[6];
    const float* rk3 = (const float*)d_in[7];
    const float* fw  = (const float*)d_in[8];
    const float* gm  = (const float*)d_in[9];
    const float* bt  = (const float*)d_in[10];
    float* out = (float*)d_out;
    float* ws  = (float*)d_ws;

    u16*   t     = (u16*)(ws + T_OFF);          // bf16 t, 33.5 MB
    u16*   xbf   = (u16*)ws + 16777216;         // bf16 x copy, second half of T region
    float* ebuf  = ws + E_OFF;
    float* stats = ws + ST_OFF;
    u16*   Abf   = (u16*)(ws + A_OFF);          // fragment-packed bf16 A
    float* cvec  = ws + CV_OFF;
    float* fwr   = ws + FW_OFF;
    u16*   Sbuf  = (u16*)out;                   // S staged bf16 in d_out, overwritten by k5

    k0_precompute<<<5,    256, 0, stream>>>(qw, kw, rk0, rk1, rk2, rk3, fw, Abf, cvec, fwr, stats);
    k1_mfma      <<<2048, 256, 0, stream>>>(x, Abf, t, xbf);
    k2_cross     <<<4096, 256, 0, stream>>>(t, Sbuf);
    k3_e         <<<1024, 256, 0, stream>>>(xbf, Sbuf, r_q, cvec, ebuf);
    k3b_stats    <<<256,  256, 0, stream>>>(ebuf, stats);
    k5_out       <<<2048, 256, 0, stream>>>(xbf, ebuf, fwr, stats, gm, bt, out);
}